// Round 6
// baseline (481.395 us; speedup 1.0000x reference)
//
#include <hip/hip_runtime.h>

#define N_NODES 8192
#define FDIM 128
#define NEG_SLOPE 0.2f

typedef short short8 __attribute__((ext_vector_type(8)));
typedef float floatx16 __attribute__((ext_vector_type(16)));

// order-preserving float->uint key for atomicMax on signed floats
__device__ inline unsigned fkey(float x) {
  unsigned b = __float_as_uint(x);
  return (b & 0x80000000u) ? ~b : (b | 0x80000000u);
}
__device__ inline float fkey_dec(unsigned kk) {
  unsigned bb = (kk & 0x80000000u) ? (kk ^ 0x80000000u) : ~kk;
  return __uint_as_float(bb);
}
__device__ inline unsigned short bf16_rn(float x) {  // round-to-nearest-even
  unsigned u = __float_as_uint(x);
  u += 0x7fffu + ((u >> 16) & 1u);
  return (unsigned short)(u >> 16);
}

// ---- Kernel A: Wh = h@W.T ; emits s1, Bj=exp(s2), Dj=exp(.2 s2), s2max,
//      and Wh repacked as bf16 hi/lo in MFMA-B-fragment order. ----
// 256 blocks x 256 thr; block = 32 rows x 128 cols; thread = 4x4 tile.
// Bfrag layout (32x32x16 bf16 B-operand): element (k,n) lives at
//   flat = ((ck*4+g)*64 + h*32 + nl)*8 + e,  k=ck*16+h*8+e, n=g*32+nl.
__global__ __launch_bounds__(256) void wh_fused_kernel(
    const float* __restrict__ h, const float* __restrict__ W,
    const float* __restrict__ a, float* __restrict__ s1g,
    float* __restrict__ Bj, float* __restrict__ Dj,
    unsigned* __restrict__ s2max_key,
    unsigned short* __restrict__ Bfh, unsigned short* __restrict__ Bfl) {
  __shared__ float Wt[FDIM * 129];   // Wt[k*129+o] = W[o][k]
  __shared__ float rows[32 * 132];   // rows[r*132+k]
  const int t = threadIdx.x;
  const int base = blockIdx.x * 32;
  for (int it = 0; it < 64; ++it) {
    int idx = t + 256 * it;          // idx = o*128+k
    int o = idx >> 7, k = idx & 127;
    Wt[k * 129 + o] = W[idx];
  }
  for (int it = 0; it < 16; ++it) {
    int idx = t + 256 * it;          // idx = r*128+col
    int r = idx >> 7, col = idx & 127;
    rows[r * 132 + col] = h[(size_t)base * FDIM + idx];
  }
  __syncthreads();
  const int c4 = (t & 31) * 4;
  const int g = t >> 5;
  float acc[4][4];
#pragma unroll
  for (int rr = 0; rr < 4; ++rr)
#pragma unroll
    for (int cc = 0; cc < 4; ++cc) acc[rr][cc] = 0.f;
  for (int k = 0; k < FDIM; ++k) {
    float4 wv = *(const float4*)&Wt[k * 129 + c4];
    float rv[4];
#pragma unroll
    for (int rr = 0; rr < 4; ++rr) rv[rr] = rows[(4 * g + rr) * 132 + k];
#pragma unroll
    for (int rr = 0; rr < 4; ++rr) {
      acc[rr][0] += rv[rr] * wv.x;
      acc[rr][1] += rv[rr] * wv.y;
      acc[rr][2] += rv[rr] * wv.z;
      acc[rr][3] += rv[rr] * wv.w;
    }
  }
  // ---- s1/s2 epilogue: width-32 shfl reduce, write s1, Bj, Dj, s2max ----
  {
    float4 a1c = *(const float4*)&a[c4];
    float4 a2c = *(const float4*)&a[FDIM + c4];
    float p1[4], p2[4];
#pragma unroll
    for (int rr = 0; rr < 4; ++rr) {
      p1[rr] = acc[rr][0] * a1c.x + acc[rr][1] * a1c.y +
               acc[rr][2] * a1c.z + acc[rr][3] * a1c.w;
      p2[rr] = acc[rr][0] * a2c.x + acc[rr][1] * a2c.y +
               acc[rr][2] * a2c.z + acc[rr][3] * a2c.w;
    }
#pragma unroll
    for (int rr = 0; rr < 4; ++rr)
      for (int off = 16; off; off >>= 1) {
        p1[rr] += __shfl_down(p1[rr], off, 32);
        p2[rr] += __shfl_down(p2[rr], off, 32);
      }
    if ((t & 31) == 0) {
      unsigned kmax = 0;
#pragma unroll
      for (int rr = 0; rr < 4; ++rr) {
        int r = base + 4 * g + rr;
        s1g[r] = p1[rr];
        Bj[r] = __expf(p2[rr]);
        Dj[r] = __expf(NEG_SLOPE * p2[rr]);
        unsigned kk = fkey(p2[rr]);
        kmax = kk > kmax ? kk : kmax;
      }
      atomicMax(s2max_key, kmax);
    }
  }
  // ---- repack acc into bf16 hi/lo B-fragment order (reuse Wt as scratch) --
  __syncthreads();                   // MAC reads of Wt/rows done
  unsigned short* hbuf = (unsigned short*)Wt;        // 4096
  unsigned short* lbuf = hbuf + 4096;                // 4096
#pragma unroll
  for (int rr = 0; rr < 4; ++rr)
#pragma unroll
    for (int cc = 0; cc < 4; ++cc) {
      float x = acc[rr][cc];
      unsigned short hb = bf16_rn(x);
      float hf = __uint_as_float(((unsigned)hb) << 16);
      unsigned short lb = bf16_rn(x - hf);
      int lr = 4 * g + rr;           // local k in [0,32)
      int n = c4 + cc;               // col in [0,128)
      int idx = (((lr >> 4) * 4 + (n >> 5)) * 64 + ((lr >> 3) & 1) * 32 +
                 (n & 31)) * 8 + (lr & 7);
      hbuf[idx] = hb;
      lbuf[idx] = lb;
    }
  __syncthreads();
  {
    const unsigned* hsrc = (const unsigned*)hbuf;
    const unsigned* lsrc = (const unsigned*)lbuf;
    unsigned* hdst = (unsigned*)(Bfh + (size_t)base * FDIM);
    unsigned* ldst = (unsigned*)(Bfl + (size_t)base * FDIM);
    for (int q = t; q < 2048; q += 256) { hdst[q] = hsrc[q]; ldst[q] = lsrc[q]; }
  }
}

// ---- Kernel B: dense P @ Wh via bf16 MFMA, A-fragments generated on the
//      fly from the adj stream. Block = 32 rows x 4096 K-cols; 4 waves split
//      K (1024 each); zero barriers/LDS in the K-loop. Wh split hi+lo bf16,
//      both MFMA'd into the same fp32 accumulator (near-fp32 B precision).
__global__ __launch_bounds__(256) void gat_mfma_kernel(
    const float* __restrict__ adj,
    const unsigned short* __restrict__ Bfh,
    const unsigned short* __restrict__ Bfl,
    const float* __restrict__ s1g, const float* __restrict__ Bj,
    const float* __restrict__ Dj, const unsigned* __restrict__ s2max_key,
    float* __restrict__ num, float* __restrict__ l_ws) {
  __shared__ float cred[4 * 32 * FDIM];   // 64 KB: per-wave C tiles
  const int t = threadIdx.x;
  const int lane = t & 63;
  const int wave = t >> 6;
  const int rowgrp = blockIdx.x >> 1;
  const int ksplit = blockIdx.x & 1;
  const int hh = lane >> 5;          // k-half within K16
  const int m0 = rowgrp * 32 + (lane & 31);
  const int kbase = ksplit * 4096 + wave * 1024;

  // per-row factors: m_i = max(0, lrelu(s1_i + s2max)) upper-bounds all e_ij
  const float s1i = s1g[m0];
  float pmv = s1i + fkey_dec(*s2max_key);
  pmv = pmv > 0.f ? pmv : NEG_SLOPE * pmv;
  const float m = fmaxf(pmv, 0.f);
  const float Ai = __expf(s1i - m);
  const float Ci = __expf(NEG_SLOPE * s1i - m);
  const float Ti = __expf(-s1i);     // cond s1+s2>0  <=>  Bj > Ti
  const float em = __expf(-m);

  const float* adj_lane = adj + (size_t)m0 * N_NODES + hh * 8;
  const float* bj_lane = Bj + hh * 8;
  const float* dj_lane = Dj + hh * 8;
  const short8* BH = (const short8*)Bfh;
  const short8* BL = (const short8*)Bfl;

  floatx16 acc0, acc1, acc2, acc3;
#pragma unroll
  for (int i = 0; i < 16; ++i) { acc0[i] = 0.f; acc1[i] = 0.f; acc2[i] = 0.f; acc3[i] = 0.f; }
  float rsum = 0.f;

#pragma unroll 2
  for (int k = kbase; k < kbase + 1024; k += 16) {
    float4 a0 = *(const float4*)(adj_lane + k);
    float4 a1 = *(const float4*)(adj_lane + k + 4);
    float4 b0 = *(const float4*)(bj_lane + k);
    float4 b1 = *(const float4*)(bj_lane + k + 4);
    float4 d0 = *(const float4*)(dj_lane + k);
    float4 d1 = *(const float4*)(dj_lane + k + 4);
    size_t fb = ((size_t)(k >> 4) * 4) * 64 + lane;
    short8 bh0 = BH[fb],       bl0 = BL[fb];
    short8 bh1 = BH[fb + 64],  bl1 = BL[fb + 64];
    short8 bh2 = BH[fb + 128], bl2 = BL[fb + 128];
    short8 bh3 = BH[fb + 192], bl3 = BL[fb + 192];

    float av[8] = {a0.x, a0.y, a0.z, a0.w, a1.x, a1.y, a1.z, a1.w};
    float bv[8] = {b0.x, b0.y, b0.z, b0.w, b1.x, b1.y, b1.z, b1.w};
    float dv[8] = {d0.x, d0.y, d0.z, d0.w, d1.x, d1.y, d1.z, d1.w};
    float pv[8];
#pragma unroll
    for (int e = 0; e < 8; ++e) {
      bool cpos = bv[e] > Ti;
      float p = (cpos ? Ai : Ci) * (cpos ? bv[e] : dv[e]);
      p = (av[e] != 0.f) ? p : em;
      pv[e] = p;
      rsum += p;
    }
    union { uint4 u; short8 s; } pk;
    pk.u.x = (unsigned)bf16_rn(pv[0]) | ((unsigned)bf16_rn(pv[1]) << 16);
    pk.u.y = (unsigned)bf16_rn(pv[2]) | ((unsigned)bf16_rn(pv[3]) << 16);
    pk.u.z = (unsigned)bf16_rn(pv[4]) | ((unsigned)bf16_rn(pv[5]) << 16);
    pk.u.w = (unsigned)bf16_rn(pv[6]) | ((unsigned)bf16_rn(pv[7]) << 16);
    short8 af = pk.s;

    acc0 = __builtin_amdgcn_mfma_f32_32x32x16_bf16(af, bh0, acc0, 0, 0, 0);
    acc0 = __builtin_amdgcn_mfma_f32_32x32x16_bf16(af, bl0, acc0, 0, 0, 0);
    acc1 = __builtin_amdgcn_mfma_f32_32x32x16_bf16(af, bh1, acc1, 0, 0, 0);
    acc1 = __builtin_amdgcn_mfma_f32_32x32x16_bf16(af, bl1, acc1, 0, 0, 0);
    acc2 = __builtin_amdgcn_mfma_f32_32x32x16_bf16(af, bh2, acc2, 0, 0, 0);
    acc2 = __builtin_amdgcn_mfma_f32_32x32x16_bf16(af, bl2, acc2, 0, 0, 0);
    acc3 = __builtin_amdgcn_mfma_f32_32x32x16_bf16(af, bh3, acc3, 0, 0, 0);
    acc3 = __builtin_amdgcn_mfma_f32_32x32x16_bf16(af, bl3, acc3, 0, 0, 0);
  }

  // ---- l: lanes l and l+32 hold the same row ----
  rsum += __shfl_xor(rsum, 32);
  if (lane < 32) atomicAdd(&l_ws[rowgrp * 32 + lane], rsum);

  // ---- C tiles -> LDS -> cross-wave sum -> atomicAdd into num ----
  // C layout (verified m74/m101): col=lane&31, row=(reg&3)+8*(reg>>2)+4*(lane>>5)
#pragma unroll
  for (int reg = 0; reg < 16; ++reg) {
    int r = (reg & 3) + 8 * (reg >> 2) + 4 * hh;
    int cbase = (wave * 32 + r) * FDIM + (lane & 31);
    cred[cbase]      = acc0[reg];
    cred[cbase + 32] = acc1[reg];
    cred[cbase + 64] = acc2[reg];
    cred[cbase + 96] = acc3[reg];
  }
  __syncthreads();
#pragma unroll
  for (int q = 0; q < 16; ++q) {
    int idx = q * 256 + t;
    int r = idx >> 7, c = idx & 127;
    float s = cred[r * FDIM + c] + cred[(32 + r) * FDIM + c] +
              cred[(64 + r) * FDIM + c] + cred[(96 + r) * FDIM + c];
    atomicAdd(&num[(size_t)(rowgrp * 32 + r) * FDIM + c], s);
  }
}

// ---- Kernel C: out = num / l ----
__global__ __launch_bounds__(256) void norm_kernel(
    const float* __restrict__ num, const float* __restrict__ l_ws,
    float* __restrict__ out) {
  int idx = blockIdx.x * 256 + threadIdx.x;       // float4 index
  float4 v = ((const float4*)num)[idx];
  float li = l_ws[idx >> 5];
  ((float4*)out)[idx] =
      make_float4(v.x / li, v.y / li, v.z / li, v.w / li);
}

extern "C" void kernel_launch(void* const* d_in, const int* in_sizes, int n_in,
                              void* d_out, int out_size, void* d_ws, size_t ws_size,
                              hipStream_t stream) {
  const float* h   = (const float*)d_in[0];
  const float* adj = (const float*)d_in[1];
  const float* W   = (const float*)d_in[2];
  const float* a   = (const float*)d_in[3];
  float* out = (float*)d_out;
  // ws layout (8.5 MB):
  // num[1048576] | l[8192] | key[1] | s1[8192] | Bj[8192] | Dj[8192]
  // | Bfh[1048576 u16] | Bfl[1048576 u16]
  float* num = (float*)d_ws;
  float* l_ws = num + (size_t)N_NODES * FDIM;
  unsigned* key = (unsigned*)(l_ws + N_NODES);
  float* s1 = (float*)(key + 1);
  float* Bj = s1 + N_NODES;
  float* Dj = Bj + N_NODES;
  unsigned short* Bfh = (unsigned short*)(Dj + N_NODES);
  unsigned short* Bfl = Bfh + (size_t)N_NODES * FDIM;

  // zero num + l + key in one shot (contiguous)
  hipMemsetAsync(num, 0, ((size_t)N_NODES * FDIM + N_NODES + 1) * sizeof(float),
                 stream);
  hipLaunchKernelGGL(wh_fused_kernel, dim3(N_NODES / 32), dim3(256), 0, stream,
                     h, W, a, s1, Bj, Dj, key, Bfh, Bfl);
  hipLaunchKernelGGL(gat_mfma_kernel, dim3(512), dim3(256), 0, stream,
                     adj, Bfh, Bfl, s1, Bj, Dj, key, num, l_ws);
  hipLaunchKernelGGL(norm_kernel, dim3(N_NODES * FDIM / 4 / 256), dim3(256), 0,
                     stream, num, l_ws, out);
}